// Round 11
// baseline (211.162 us; speedup 1.0000x reference)
//
#include <hip/hip_runtime.h>
#include <hip/hip_bf16.h>

#define N0 4096
#define N1 16384
#define HID 128
#define LAT 64
#define DIM 3
#define NAUG 21
#define JTOT 512    // xl(128) | xr(128) | lins(128) | pe(128)
#define NG 5        // k-groups (K padded 131->160)

typedef __attribute__((ext_vector_type(8))) short bf16x8;
typedef __attribute__((ext_vector_type(4))) float f32x4;

__device__ __constant__ int c_aug[NAUG] = {1,2,3,4,5,6,7,8,9,10,11,12,13,14,
                                           15,16,17,18,19,21,24};

__device__ __forceinline__ unsigned short f2bf(float v) {
    __hip_bfloat16 b = __float2bfloat16(v);
    return *reinterpret_cast<unsigned short*>(&b);
}

// DPP-based cross-lane add: p + lane[ctrl-perm(lane)].p  -- VALU pipe, no LDS.
// 0xB1 = quad_perm[1,0,3,2] (xor1); 0x4E = quad_perm[2,3,0,1] (xor2);
// 0x128 = row_ror:8 (== xor8 once bits 0,1 are reduced);
// 0x124 = row_ror:4 (== xor4 once bits 0,1,3 are reduced).
template<int CTRL>
__device__ __forceinline__ float dpp_xadd(float p) {
    return p + __int_as_float(__builtin_amdgcn_mov_dpp(
        __float_as_int(p), CTRL, 0xF, 0xF, true));
}

// 32-lane sum: 4 DPP stages + 1 swizzle stage (xor16 crosses 16-lane rows).
__device__ __forceinline__ float reduce32(float p) {
    p = dpp_xadd<0xB1>(p);
    p = dpp_xadd<0x4E>(p);
    p = dpp_xadd<0x128>(p);
    p = dpp_xadd<0x124>(p);
    p += __shfl_xor(p, 16, 64);
    return p;
}

// ---------------------------------------------------------------------------
// knn geometry: 16 chunks x 256 x-points, 64 y-parts per chunk.
// 1024 knn blocks -> 4 blocks/CU = 16 waves/CU during the knn tail.
// ---------------------------------------------------------------------------
#define KCH 16
#define KCS 256
#define KNN_XPARTS 64
#define KNN_BLOCKS (KCH * KNN_XPARTS)    // 1024

// ---------------------------------------------------------------------------
// prep element space (incl. Wt0: written in A, read by lin0 in B --
// cross-dispatch, stream-ordered; NEVER same-dispatch (R6 race))
// ---------------------------------------------------------------------------
#define WSWZ_PER_LAYER 81920   // 160*512
#define H0G4 131072            // (N0/16)*64*8
#define H1G4 524288            // (N1/16)*64*8
#define P_NSWZ (4 * WSWZ_PER_LAYER)          // 327680
#define P_B0 P_NSWZ                          // bias_cat start
#define P_B1 (P_B0 + 4 * JTOT)               // Wt0 start
#define P_B2 (P_B1 + 64 * 128)               // h0 g4 start
#define P_B3 (P_B2 + H0G4)                   // h1B g4 start
#define P_B4 (P_B3 + H1G4)                   // 993280 total
#define PREP_BLOCKS 3880                     // 993280 / 256

__global__ __launch_bounds__(256)
void prep_knn_kernel(const float* __restrict__ Wl,
                     const float* __restrict__ Wr,
                     const float* __restrict__ We,
                     const float* __restrict__ linsW,
                     const float* __restrict__ bl,
                     const float* __restrict__ br,
                     const float* __restrict__ linsb,
                     const float* __restrict__ lin0W,
                     const float* __restrict__ pos0,
                     const float* __restrict__ pos1,
                     unsigned short* __restrict__ Wswz,
                     float* __restrict__ bias_cat,
                     float* __restrict__ Wt0,
                     unsigned short* __restrict__ hswz0A,
                     unsigned short* __restrict__ hswz0B,
                     unsigned short* __restrict__ hswz1B,
                     float* __restrict__ pb_d,
                     int* __restrict__ pb_i) {
    __shared__ float4 sx[KCS];   // knn branch only: 4KB (x, y, z, |x|^2)

    if (blockIdx.x < KNN_BLOCKS) {
        // ---- knn_part: one 256-x chunk vs 256 y ----
        int tid = threadIdx.x;
        int chunk = blockIdx.x >> 6;     // 0..15
        int xpart = blockIdx.x & 63;     // 0..63
        {
            const float* p = &pos0[(chunk * KCS + tid) * 3];
            float x = p[0], y = p[1], z = p[2];
            sx[tid] = make_float4(x, y, z, x * x + y * y + z * z);
        }
        __syncthreads();
        int y = xpart * 256 + tid;
        float p0 = pos1[y * 3], p1 = pos1[y * 3 + 1], p2 = pos1[y * 3 + 2];
        float m0 = -2.0f * p0, m1 = -2.0f * p1, m2 = -2.0f * p2;
        float sy = p0 * p0 + p1 * p1 + p2 * p2;
        float bd0 = 1e30f, bd1 = 1e30f, bd2 = 1e30f;
        int bi0 = 0, bi1 = 0, bi2 = 0;
        int gbase = chunk * KCS;
#pragma unroll 4
        for (int i = 0; i < KCS; i += 4) {
            float4 s[4];
#pragma unroll
            for (int v = 0; v < 4; ++v) s[v] = sx[i + v];
#pragma unroll
            for (int v = 0; v < 4; ++v) {
                int gi = gbase + i + v;
                float t = fmaf(m0, s[v].x, s[v].w);
                t = fmaf(m1, s[v].y, t);
                t = fmaf(m2, s[v].z, t);
                t += sy;
                bool c0 = t < bd0;
                bool c1 = t < bd1;
                bool c2 = t < bd2;
                float n0 = fminf(bd0, t);
                float n1 = __builtin_amdgcn_fmed3f(bd0, bd1, t);
                float n2 = __builtin_amdgcn_fmed3f(bd1, bd2, t);
                int j0 = c0 ? gi : bi0;
                int j1 = c0 ? bi0 : (c1 ? gi : bi1);
                int j2 = c1 ? bi1 : (c2 ? gi : bi2);
                bd0 = n0; bd1 = n1; bd2 = n2;
                bi0 = j0; bi1 = j1; bi2 = j2;
            }
        }
        int base = (chunk * N1 + y) * 3;
        pb_d[base] = bd0; pb_d[base + 1] = bd1; pb_d[base + 2] = bd2;
        pb_i[base] = bi0; pb_i[base + 1] = bi1; pb_i[base + 2] = bi2;
        return;
    }

    // ---- prep ----
    int tid = (blockIdx.x - KNN_BLOCKS) * blockDim.x + threadIdx.x;
    if (tid < P_NSWZ) {
        int c = tid / WSWZ_PER_LAYER;
        int r = tid - c * WSWZ_PER_LAYER;    // ((nt*5+g)*64+l)*8+j
        int nt = r / 2560;
        int g  = (r / 512) % 5;
        int l  = (r / 8) % 64;
        int j  = r % 8;
        int k  = g * 32 + (l >> 4) * 8 + j;
        int n  = nt * 16 + (l & 15);
        float v = 0.0f;
        if (k < 131) {
            if (n < 128)      v = Wl[(c * 128 + n) * 131 + k];
            else if (n < 256) v = Wr[(c * 128 + (n - 128)) * 131 + k];
            else if (n < 384) v = linsW[(c * 128 + (n - 256)) * 131 + k];
            else              v = (k >= 128) ? We[(c * 128 + (n - 384)) * 3 + (k - 128)]
                                             : 0.0f;
        }
        Wswz[tid] = f2bf(v);
    } else if (tid < P_B1) {                 // bias_cat
        int idx = tid - P_B0;
        int c = idx / JTOT;
        int j = idx - c * JTOT;
        float v;
        if (j < 128)        v = bl[c * 128 + j];
        else if (j < 256)   v = br[c * 128 + (j - 128)];
        else if (j < 384)   v = linsb[c * 128 + (j - 256)];
        else                v = 0.0f;
        bias_cat[idx] = v;
    } else if (tid < P_B2) {                 // Wt0 (read by lin0 in kernel B)
        int idx = tid - P_B1;
        int k = idx / 128;
        int j = idx - k * 128;
        Wt0[idx] = lin0W[j * 64 + k];
    } else if (tid < P_B3) {                 // hswz0 g=4 plane (both buffers)
        int r = tid - P_B2;                  // (mt*64 + l)*8 + j
        int j = r & 7;
        int l = (r >> 3) & 63;
        int mt = r >> 9;
        int row = mt * 16 + (l & 15);
        int k = 128 + (l >> 4) * 8 + j;
        float v = (k < 131) ? pos0[row * 3 + (k - 128)] : 0.0f;
        unsigned short bv = f2bf(v);
        size_t idx = (size_t)((mt * 5 + 4) * 64 + l) * 8 + j;
        hswz0A[idx] = bv;
        hswz0B[idx] = bv;
    } else if (tid < P_B4) {                 // hswz1B g=4 plane (h1A deleted)
        int r = tid - P_B3;
        int j = r & 7;
        int l = (r >> 3) & 63;
        int mt = r >> 9;
        int row = mt * 16 + (l & 15);
        int k = 128 + (l >> 4) * 8 + j;
        float v = (k < 131) ? pos1[row * 3 + (k - 128)] : 0.0f;
        hswz1B[(size_t)((mt * 5 + 4) * 64 + l) * 8 + j] = f2bf(v);
    }
}

// ---------------------------------------------------------------------------
// Kernel B: knn_merge (blocks 0..127) || lin0 (blocks 128..4223).
// merge reads pb from A (stream-ordered); lin0 reads Wt0 from A (ordered).
// ---------------------------------------------------------------------------
#define MERGE_BLOCKS 128       // 16384 / 128

__global__ __launch_bounds__(128)
void lin0_merge_kernel(const float* __restrict__ latent,
                       const float* __restrict__ Wt0,
                       const float* __restrict__ b,
                       unsigned short* __restrict__ hswz0,
                       const float* __restrict__ pb_d,
                       const int* __restrict__ pb_i,
                       int* __restrict__ knn_idx,
                       float* __restrict__ knn_w) {
    __shared__ float lrow[64];

    if (blockIdx.x < MERGE_BLOCKS) {
        // ---- knn_merge: 16 chunks x 3 entries ----
        int y = blockIdx.x * 128 + threadIdx.x;
        float bd0 = 1e30f, bd1 = 1e30f, bd2 = 1e30f;
        int bi0 = 0, bi1 = 0, bi2 = 0;
        for (int c = 0; c < KCH; ++c) {
            int base = (c * N1 + y) * 3;
#pragma unroll
            for (int t3 = 0; t3 < 3; ++t3) {
                float t = pb_d[base + t3];
                int gi = pb_i[base + t3];
                bool c0 = t < bd0;
                bool c1 = t < bd1;
                bool c2 = t < bd2;
                float n0 = fminf(bd0, t);
                float n1 = __builtin_amdgcn_fmed3f(bd0, bd1, t);
                float n2 = __builtin_amdgcn_fmed3f(bd1, bd2, t);
                int j0 = c0 ? gi : bi0;
                int j1 = c0 ? bi0 : (c1 ? gi : bi1);
                int j2 = c1 ? bi1 : (c2 ? gi : bi2);
                bd0 = n0; bd1 = n1; bd2 = n2;
                bi0 = j0; bi1 = j1; bi2 = j2;
            }
        }
        knn_idx[y * 3]     = bi0;
        knn_idx[y * 3 + 1] = bi1;
        knn_idx[y * 3 + 2] = bi2;
        knn_w[y * 3]     = 1.0f / fmaxf(bd0, 1e-16f);
        knn_w[y * 3 + 1] = 1.0f / fmaxf(bd1, 1e-16f);
        knn_w[y * 3 + 2] = 1.0f / fmaxf(bd2, 1e-16f);
        return;
    }

    // ---- lin0 ----
    int n = blockIdx.x - MERGE_BLOCKS;
    int j = threadIdx.x;
    if (j < 64) lrow[j] = latent[n * 64 + j];
    __syncthreads();
    float acc = b[j];
#pragma unroll 8
    for (int k = 0; k < 64; ++k) acc += lrow[k] * Wt0[k * 128 + j];
    int g = j >> 5, sub = (j >> 3) & 3, jj = j & 7;
    hswz0[(size_t)(((n >> 4) * 5 + g) * 64 + sub * 16 + (n & 15)) * 8 + jj] = f2bf(acc);
}

// ---------------------------------------------------------------------------
// Fused GATv2 layer body.  lin result in LDS (lin_s); reduce via 4 DPP + 1
// swizzle.  A-fragments come from global hswz OR a pre-staged LDS copy
// (hloc, used by the interp-fused L2 kernel).
// mode 0: f32 x out; mode 1: bf16 A-fragments; mode 2: fused output head.
// ---------------------------------------------------------------------------
#define WROW 40
#define FSTR 132

__device__ __forceinline__ void layer_body(
        const unsigned short* __restrict__ hswz,     // global (or null)
        const unsigned short* hloc,                  // LDS-staged (or null)
        const unsigned short* __restrict__ Wswz,
        const float* __restrict__ bias_cat,
        const float* __restrict__ att,
        const float* __restrict__ bias,
        float* __restrict__ xout,
        unsigned short* __restrict__ hout,
        const float* __restrict__ outW,
        const float* __restrict__ outb,
        const float* __restrict__ pos1,
        int mode, int N, int mt0,
        float (*xls_s)[FSTR], float (*pes_s)[FSTR], float (*xr_s)[FSTR],
        float (*lin_s)[FSTR]) {
    int tid = threadIdx.x;
    int w = tid >> 6;               // 0..7
    int l = tid & 63;
    int quad = l >> 4, lcol = l & 15;
    int n0 = mt0 * 16;
    int MT = N >> 4;

    // ---- GEMM phase ----
    bf16x8 a[3][NG];
    if (hloc) {
#pragma unroll
        for (int i = 0; i < 3; ++i)
#pragma unroll
            for (int g = 0; g < NG; ++g)
                a[i][g] = *(const bf16x8*)&hloc[(size_t)(((i * NG + g) * 64) + l) * 8];
        __syncthreads();            // hloc overlays xls_s: drain reads first
    } else {
#pragma unroll
        for (int i = 0; i < 3; ++i) {
            int mt = mt0 - 2 + i;
            if (mt < 0) mt += MT;
#pragma unroll
            for (int g = 0; g < NG; ++g)
                a[i][g] = *(const bf16x8*)&hswz[(size_t)((mt * NG + g) * 64 + l) * 8];
        }
    }

#pragma unroll
    for (int i = 0; i < 4; ++i) {
        int b = i * 8 + w;          // 0..31, wave-uniform
        int colbase = (b & 7) * 16;
        int ntw, kind;              // kind: 0 xl(3mt) 1 pe(3mt) 2 xr 3 lin
        if (b < 8)       { ntw = b;      kind = 0; }
        else if (b < 16) { ntw = 16 + b; kind = 1; }
        else if (b < 24) { ntw = b - 8;  kind = 2; }
        else             { ntw = b - 8;  kind = 3; }
        bf16x8 bf[NG];
#pragma unroll
        for (int g = 0; g < NG; ++g)
            bf[g] = *(const bf16x8*)&Wswz[(size_t)((ntw * NG + g) * 64 + l) * 8];
        float bv = bias_cat[ntw * 16 + lcol];
        if (kind < 2) {
            float (*dst)[FSTR] = (kind == 0) ? xls_s : pes_s;
#pragma unroll
            for (int m = 0; m < 3; ++m) {
                f32x4 c = {bv, bv, bv, bv};
#pragma unroll
                for (int g = 0; g < NG; ++g)
                    c = __builtin_amdgcn_mfma_f32_16x16x32_bf16(a[m][g], bf[g], c, 0, 0, 0);
                if (m == 0) {
                    if (quad >= 2) {
                        int w0 = (quad - 2) * 4;
#pragma unroll
                        for (int r = 0; r < 4; ++r) dst[w0 + r][colbase + lcol] = c[r];
                    }
                } else {
                    int w0 = m * 16 - 8 + quad * 4;
#pragma unroll
                    for (int r = 0; r < 4; ++r) dst[w0 + r][colbase + lcol] = c[r];
                }
            }
        } else {
            f32x4 c = {bv, bv, bv, bv};
#pragma unroll
            for (int g = 0; g < NG; ++g)
                c = __builtin_amdgcn_mfma_f32_16x16x32_bf16(a[2][g], bf[g], c, 0, 0, 0);
            float (*dst)[FSTR] = (kind == 2) ? xr_s : lin_s;
            int w0 = quad * 4;
#pragma unroll
            for (int r = 0; r < 4; ++r) dst[w0 + r][colbase + lcol] = c[r];
        }
    }
    __syncthreads();

    // ---- Gather phase (max-free softmax; 32 lanes x 4 cols per dst row) ----
    int qh = l >> 5;                // 0..1
    int t = l & 31;                 // 0..31
    int dl = w * 2 + qh;            // 0..15
    int d = n0 + dl;
    int selfrow = dl + 24;
    int i0 = t * 4;

    f32x4 linv = *(const f32x4*)&lin_s[dl][i0];

    float att4[4], base[4], xld[4], pesum[4], o[4];
    {
        f32x4 a0 = *(const f32x4*)&att[i0];
        f32x4 r0 = *(const f32x4*)&xr_s[dl][i0];
        f32x4 x0 = *(const f32x4*)&xls_s[selfrow][i0];
        f32x4 p0 = *(const f32x4*)&pes_s[selfrow][i0];
#pragma unroll
        for (int j = 0; j < 4; ++j) {
            att4[j] = a0[j];
            xld[j]  = x0[j];
            base[j] = r0[j] + p0[j];
            pesum[j] = 0.0f;
            o[j] = 0.0f;
        }
    }

    float den = 0.0f;

#pragma unroll
    for (int k = 0; k < NAUG; ++k) {
        int lr = selfrow - c_aug[k];
        float xls[4], pes[4];
        *(f32x4*)&xls[0] = *(const f32x4*)&xls_s[lr][i0];
        *(f32x4*)&pes[0] = *(const f32x4*)&pes_s[lr][i0];
        float p = 0.0f;
#pragma unroll
        for (int j = 0; j < 4; ++j) {
            float mm = xls[j] + base[j] - pes[j];
            mm = mm > 0.0f ? mm : 0.2f * mm;
            p = fmaf(att4[j], mm, p);
            pesum[j] += pes[j];
        }
        p = reduce32(p);
        float wgt = __expf(p);
        den += wgt;
#pragma unroll
        for (int j = 0; j < 4; ++j) o[j] = fmaf(wgt, xls[j], o[j]);
    }
    {   // self loop: eattr = ped - mean(pes); m = xld + base - mean
        const float inv21 = 1.0f / 21.0f;
        float p = 0.0f;
#pragma unroll
        for (int j = 0; j < 4; ++j) {
            float mm = xld[j] + base[j] - pesum[j] * inv21;
            mm = mm > 0.0f ? mm : 0.2f * mm;
            p = fmaf(att4[j], mm, p);
        }
        p = reduce32(p);
        float wgt = __expf(p);
        den += wgt;
#pragma unroll
        for (int j = 0; j < 4; ++j) o[j] = fmaf(wgt, xld[j], o[j]);
    }

    float inv = 1.0f / (den + 1e-16f);
    float res[4];
    {
        f32x4 b0 = *(const f32x4*)&bias[i0];
#pragma unroll
        for (int j = 0; j < 4; ++j) {
            float v = o[j] * inv + b0[j];
            v = v > 0.0f ? v : __expf(v) - 1.0f;
            res[j] = v + linv[j];
        }
    }

    if (mode == 0) {
        *(f32x4*)&xout[(size_t)d * 128 + i0] = *(f32x4*)&res[0];
    } else if (mode == 1) {
        unsigned short ob[4];
#pragma unroll
        for (int j = 0; j < 4; ++j) ob[j] = f2bf(res[j]);
        int g = i0 >> 5, sub = (i0 >> 3) & 3, jj = i0 & 7;
        *(uint2*)&hout[(size_t)((((d >> 4) * 5 + g) * 64) + sub * 16 + (d & 15)) * 8 + jj]
            = *(uint2*)ob;
    } else {                        // mode 2: fused output head
        float po[3];
#pragma unroll
        for (int o3 = 0; o3 < 3; ++o3) {
            const float* wr = &outW[o3 * 131 + i0];
            float p = res[0] * wr[0];
            p = fmaf(res[1], wr[1], p);
            p = fmaf(res[2], wr[2], p);
            p = fmaf(res[3], wr[3], p);
            p = reduce32(p);
            po[o3] = p;
        }
        if (t == 0) {
            float p0 = pos1[d * 3], p1 = pos1[d * 3 + 1], p2 = pos1[d * 3 + 2];
#pragma unroll
            for (int o3 = 0; o3 < 3; ++o3) {
                xout[d * 3 + o3] = po[o3] + outb[o3] + p0 * outW[o3 * 131 + 128]
                                 + p1 * outW[o3 * 131 + 129] + p2 * outW[o3 * 131 + 130];
            }
        }
    }
}

__global__ __launch_bounds__(512, 2)
void fused_layer_kernel(const unsigned short* __restrict__ hswz,
                        const unsigned short* __restrict__ Wswz,
                        const float* __restrict__ bias_cat,
                        const float* __restrict__ att,
                        const float* __restrict__ bias,
                        float* __restrict__ xout,
                        unsigned short* __restrict__ hout,
                        const float* __restrict__ outW,
                        const float* __restrict__ outb,
                        const float* __restrict__ pos1,
                        int mode, int N) {
    __shared__ __align__(16) float xls_s[WROW][FSTR];
    __shared__ __align__(16) float pes_s[WROW][FSTR];
    __shared__ __align__(16) float xr_s[16][FSTR];
    __shared__ __align__(16) float lin_s[16][FSTR];
    layer_body(hswz, nullptr, Wswz, bias_cat, att, bias, xout, hout,
               outW, outb, pos1, mode, N, blockIdx.x,
               xls_s, pes_s, xr_s, lin_s);
}

// ---------------------------------------------------------------------------
// L2' = interp fused into layer 2 (R11).  Each block computes its OWN 48
// rows (tiles mt0-2..mt0) of interpolated x1 as bf16 fragments into a 15KB
// LDS overlay of xls_s (xls_s not written until after fragments are in
// registers; block-uniform barriers).  No cross-block deps -> race-free.
// Interp math is expression-identical to the old interp_kernel.
// ---------------------------------------------------------------------------
__global__ __launch_bounds__(512, 2)
void fused_layer2_kernel(const float* __restrict__ bufA,
                         const int* __restrict__ knn_idx,
                         const float* __restrict__ knn_w,
                         const float* __restrict__ pos1,
                         const unsigned short* __restrict__ Wswz,
                         const float* __restrict__ bias_cat,
                         const float* __restrict__ att,
                         const float* __restrict__ bias,
                         unsigned short* __restrict__ hout) {
    __shared__ __align__(16) float xls_s[WROW][FSTR];
    __shared__ __align__(16) float pes_s[WROW][FSTR];
    __shared__ __align__(16) float xr_s[16][FSTR];
    __shared__ __align__(16) float lin_s[16][FSTR];

    unsigned short* hloc = (unsigned short*)&xls_s[0][0];   // 15360B <= 21120B
    int tid = threadIdx.x;
    int mt0 = blockIdx.x;
    int MT = N1 >> 4;

    // stage fragments for tiles mt0-2..mt0: item = ((i*NG+g)*64+l)*4 + jp,
    // each item packs cols (2jp, 2jp+1) of h[y][g*32+(l>>4)*8+...]
    for (int item = tid; item < 3 * NG * 64 * 4; item += 512) {
        int jp = item & 3;
        int l  = (item >> 2) & 63;
        int gq = item >> 8;              // i*NG+g
        int g  = gq % NG;
        int i  = gq / NG;
        int mt = mt0 - 2 + i;
        if (mt < 0) mt += MT;
        int y  = mt * 16 + (l & 15);
        int col = g * 32 + ((l >> 4) << 3) + 2 * jp;
        unsigned int packed;
        if (col < 128) {
            float w0 = knn_w[y * 3], w1 = knn_w[y * 3 + 1], w2 = knn_w[y * 3 + 2];
            int j0 = knn_idx[y * 3], j1 = knn_idx[y * 3 + 1], j2 = knn_idx[y * 3 + 2];
            float inv = 1.0f / (w0 + w1 + w2);
            float2 a = *(const float2*)&bufA[(size_t)j0 * 128 + col];
            float2 b = *(const float2*)&bufA[(size_t)j1 * 128 + col];
            float2 c = *(const float2*)&bufA[(size_t)j2 * 128 + col];
            float rx = (w0 * a.x + w1 * b.x + w2 * c.x) * inv;
            float ry = (w0 * a.y + w1 * b.y + w2 * c.y) * inv;
            packed = (unsigned int)f2bf(rx) | ((unsigned int)f2bf(ry) << 16);
        } else {
            float v0 = (col < 131) ? pos1[y * 3 + (col - 128)] : 0.0f;
            float v1 = (col + 1 < 131) ? pos1[y * 3 + (col - 127)] : 0.0f;
            packed = (unsigned int)f2bf(v0) | ((unsigned int)f2bf(v1) << 16);
        }
        *(unsigned int*)&hloc[(size_t)item * 2] = packed;
    }
    __syncthreads();

    layer_body(nullptr, hloc, Wswz, bias_cat, att, bias, nullptr, hout,
               nullptr, nullptr, nullptr, 1, N1, mt0,
               xls_s, pes_s, xr_s, lin_s);
}

// ---------------------------------------------------------------------------
extern "C" void kernel_launch(void* const* d_in, const int* in_sizes, int n_in,
                              void* d_out, int out_size, void* d_ws, size_t ws_size,
                              hipStream_t stream) {
    (void)in_sizes; (void)n_in; (void)out_size; (void)ws_size;
    const float* latent   = (const float*)d_in[0];
    const float* pos0     = (const float*)d_in[1];
    const float* pos1     = (const float*)d_in[2];
    const float* conv_Wl  = (const float*)d_in[5];
    const float* conv_bl  = (const float*)d_in[6];
    const float* conv_Wr  = (const float*)d_in[7];
    const float* conv_br  = (const float*)d_in[8];
    const float* conv_We  = (const float*)d_in[9];
    const float* conv_att = (const float*)d_in[10];
    const float* conv_bias= (const float*)d_in[11];
    const float* lin0_W   = (const float*)d_in[12];
    const float* lin0_b   = (const float*)d_in[13];
    const float* lins_W   = (const float*)d_in[14];
    const float* lins_b   = (const float*)d_in[15];
    const float* out_W    = (const float*)d_in[16];
    const float* out_b    = (const float*)d_in[17];
    float* out = (float*)d_out;

    char* ws = (char*)d_ws;
    unsigned short* Wswz = (unsigned short*)ws; ws += (size_t)4 * WSWZ_PER_LAYER * 2;
    float* bias_cat = (float*)ws;  ws += (size_t)4 * JTOT * 4;
    float* Wt0      = (float*)ws;  ws += (size_t)64 * 128 * 4;
    unsigned short* hswz0A = (unsigned short*)ws; ws += (size_t)(N0 / 16) * NG * 64 * 8 * 2;
    unsigned short* hswz0B = (unsigned short*)ws; ws += (size_t)(N0 / 16) * NG * 64 * 8 * 2;
    unsigned short* hswz1B = (unsigned short*)ws; ws += (size_t)(N1 / 16) * NG * 64 * 8 * 2;
    float* bufA     = (float*)ws;  ws += (size_t)N0 * 128 * 4;
    float* pb_d     = (float*)ws;  ws += (size_t)KCH * N1 * 3 * 4;
    int*   pb_i     = (int*)ws;    ws += (size_t)KCH * N1 * 3 * 4;
    int*   knn_idx  = (int*)ws;    ws += (size_t)N1 * 3 * 4;
    float* knn_w    = (float*)ws;  ws += (size_t)N1 * 3 * 4;

    // A: knn_part (1024 blocks, first) || prep (3880 blocks)
    prep_knn_kernel<<<KNN_BLOCKS + PREP_BLOCKS, 256, 0, stream>>>(
        conv_Wl, conv_Wr, conv_We, lins_W, conv_bl, conv_br, lins_b, lin0_W,
        pos0, pos1, Wswz, bias_cat, Wt0, hswz0A, hswz0B, hswz1B,
        pb_d, pb_i);

    // B: knn_merge (128 blocks) || lin0 (4096 blocks)
    lin0_merge_kernel<<<MERGE_BLOCKS + N0, 128, 0, stream>>>(
        latent, Wt0, lin0_b, hswz0A, pb_d, pb_i, knn_idx, knn_w);

    // layer 0: h0A -> h0B (bf16 frags);  layer 1: h0B -> bufA (f32)
    fused_layer_kernel<<<N0 / 16, 512, 0, stream>>>(
        hswz0A, Wswz + (size_t)0 * WSWZ_PER_LAYER, bias_cat + 0 * JTOT,
        conv_att + 0 * 128, conv_bias + 0 * 128, nullptr, hswz0B,
        nullptr, nullptr, nullptr, 1, N0);
    fused_layer_kernel<<<N0 / 16, 512, 0, stream>>>(
        hswz0B, Wswz + (size_t)1 * WSWZ_PER_LAYER, bias_cat + 1 * JTOT,
        conv_att + 1 * 128, conv_bias + 1 * 128, bufA, nullptr,
        nullptr, nullptr, nullptr, 0, N0);

    // layer 2 (interp fused): bufA -> h1B
    fused_layer2_kernel<<<N1 / 16, 512, 0, stream>>>(
        bufA, knn_idx, knn_w, pos1,
        Wswz + (size_t)2 * WSWZ_PER_LAYER, bias_cat + 2 * JTOT,
        conv_att + 2 * 128, conv_bias + 2 * 128, hswz1B);

    // layer 3: h1B -> out (fused output head)
    fused_layer_kernel<<<N1 / 16, 512, 0, stream>>>(
        hswz1B, Wswz + (size_t)3 * WSWZ_PER_LAYER, bias_cat + 3 * JTOT,
        conv_att + 3 * 128, conv_bias + 3 * 128, out, nullptr,
        out_W, out_b, pos1, 2, N1);
}

// Round 13
// 201.723 us; speedup vs baseline: 1.0468x; 1.0468x over previous
//
#include <hip/hip_runtime.h>
#include <hip/hip_bf16.h>

#define N0 4096
#define N1 16384
#define HID 128
#define LAT 64
#define DIM 3
#define NAUG 21
#define JTOT 512    // xl(128) | xr(128) | lins(128) | pe(128)
#define NG 5        // k-groups (K padded 131->160)

typedef __attribute__((ext_vector_type(8))) short bf16x8;
typedef __attribute__((ext_vector_type(4))) float f32x4;

__device__ __constant__ int c_aug[NAUG] = {1,2,3,4,5,6,7,8,9,10,11,12,13,14,
                                           15,16,17,18,19,21,24};

__device__ __forceinline__ unsigned short f2bf(float v) {
    __hip_bfloat16 b = __float2bfloat16(v);
    return *reinterpret_cast<unsigned short*>(&b);
}

// DPP-based cross-lane add: p + lane[ctrl-perm(lane)].p  -- VALU pipe, no LDS.
// 0xB1 = quad_perm[1,0,3,2] (xor1); 0x4E = quad_perm[2,3,0,1] (xor2);
// 0x128 = row_ror:8 (== xor8 once bits 0,1 are reduced);
// 0x124 = row_ror:4 (== xor4 once bits 0,1,3 are reduced).
template<int CTRL>
__device__ __forceinline__ float dpp_xadd(float p) {
    return p + __int_as_float(__builtin_amdgcn_mov_dpp(
        __float_as_int(p), CTRL, 0xF, 0xF, true));
}

// 32-lane sum: 4 DPP stages + 1 swizzle stage (xor16 crosses 16-lane rows).
__device__ __forceinline__ float reduce32(float p) {
    p = dpp_xadd<0xB1>(p);
    p = dpp_xadd<0x4E>(p);
    p = dpp_xadd<0x128>(p);
    p = dpp_xadd<0x124>(p);
    p += __shfl_xor(p, 16, 64);
    return p;
}

// ---------------------------------------------------------------------------
// knn geometry: 16 chunks x 256 x-points, 64 y-parts per chunk.
// 1024 knn blocks -> 4 blocks/CU = 16 waves/CU during the knn tail.
// ---------------------------------------------------------------------------
#define KCH 16
#define KCS 256
#define KNN_XPARTS 64
#define KNN_BLOCKS (KCH * KNN_XPARTS)    // 1024

// ---------------------------------------------------------------------------
// prep element space (incl. Wt0: written in A, read by lin0 in B --
// cross-dispatch, stream-ordered; NEVER same-dispatch (R6 race))
// ---------------------------------------------------------------------------
#define WSWZ_PER_LAYER 81920   // 160*512
#define H0G4 131072            // (N0/16)*64*8
#define H1G4 524288            // (N1/16)*64*8
#define P_NSWZ (4 * WSWZ_PER_LAYER)          // 327680
#define P_B0 P_NSWZ                          // bias_cat start
#define P_B1 (P_B0 + 4 * JTOT)               // Wt0 start
#define P_B2 (P_B1 + 64 * 128)               // h0 g4 start
#define P_B3 (P_B2 + H0G4)                   // h1 g4 start
#define P_B4 (P_B3 + H1G4)                   // 993280 total
#define PREP_BLOCKS 3880                     // 993280 / 256

__global__ __launch_bounds__(256)
void prep_knn_kernel(const float* __restrict__ Wl,
                     const float* __restrict__ Wr,
                     const float* __restrict__ We,
                     const float* __restrict__ linsW,
                     const float* __restrict__ bl,
                     const float* __restrict__ br,
                     const float* __restrict__ linsb,
                     const float* __restrict__ lin0W,
                     const float* __restrict__ pos0,
                     const float* __restrict__ pos1,
                     unsigned short* __restrict__ Wswz,
                     float* __restrict__ bias_cat,
                     float* __restrict__ Wt0,
                     unsigned short* __restrict__ hswz0A,
                     unsigned short* __restrict__ hswz0B,
                     unsigned short* __restrict__ hswz1A,
                     unsigned short* __restrict__ hswz1B,
                     float* __restrict__ pb_d,
                     int* __restrict__ pb_i) {
    __shared__ float4 sx[KCS];   // knn branch only: 4KB (x, y, z, |x|^2)

    if (blockIdx.x < KNN_BLOCKS) {
        // ---- knn_part: one 256-x chunk vs 256 y ----
        int tid = threadIdx.x;
        int chunk = blockIdx.x >> 6;     // 0..15
        int xpart = blockIdx.x & 63;     // 0..63
        {
            const float* p = &pos0[(chunk * KCS + tid) * 3];
            float x = p[0], y = p[1], z = p[2];
            sx[tid] = make_float4(x, y, z, x * x + y * y + z * z);
        }
        __syncthreads();
        int y = xpart * 256 + tid;
        float p0 = pos1[y * 3], p1 = pos1[y * 3 + 1], p2 = pos1[y * 3 + 2];
        float m0 = -2.0f * p0, m1 = -2.0f * p1, m2 = -2.0f * p2;
        float sy = p0 * p0 + p1 * p1 + p2 * p2;
        float bd0 = 1e30f, bd1 = 1e30f, bd2 = 1e30f;
        int bi0 = 0, bi1 = 0, bi2 = 0;
        int gbase = chunk * KCS;
#pragma unroll 4
        for (int i = 0; i < KCS; i += 4) {
            float4 s[4];
#pragma unroll
            for (int v = 0; v < 4; ++v) s[v] = sx[i + v];
#pragma unroll
            for (int v = 0; v < 4; ++v) {
                int gi = gbase + i + v;
                float t = fmaf(m0, s[v].x, s[v].w);
                t = fmaf(m1, s[v].y, t);
                t = fmaf(m2, s[v].z, t);
                t += sy;
                bool c0 = t < bd0;
                bool c1 = t < bd1;
                bool c2 = t < bd2;
                float n0 = fminf(bd0, t);
                float n1 = __builtin_amdgcn_fmed3f(bd0, bd1, t);
                float n2 = __builtin_amdgcn_fmed3f(bd1, bd2, t);
                int j0 = c0 ? gi : bi0;
                int j1 = c0 ? bi0 : (c1 ? gi : bi1);
                int j2 = c1 ? bi1 : (c2 ? gi : bi2);
                bd0 = n0; bd1 = n1; bd2 = n2;
                bi0 = j0; bi1 = j1; bi2 = j2;
            }
        }
        int base = (chunk * N1 + y) * 3;
        pb_d[base] = bd0; pb_d[base + 1] = bd1; pb_d[base + 2] = bd2;
        pb_i[base] = bi0; pb_i[base + 1] = bi1; pb_i[base + 2] = bi2;
        return;
    }

    // ---- prep ----
    int tid = (blockIdx.x - KNN_BLOCKS) * blockDim.x + threadIdx.x;
    if (tid < P_NSWZ) {
        int c = tid / WSWZ_PER_LAYER;
        int r = tid - c * WSWZ_PER_LAYER;    // ((nt*5+g)*64+l)*8+j
        int nt = r / 2560;
        int g  = (r / 512) % 5;
        int l  = (r / 8) % 64;
        int j  = r % 8;
        int k  = g * 32 + (l >> 4) * 8 + j;
        int n  = nt * 16 + (l & 15);
        float v = 0.0f;
        if (k < 131) {
            if (n < 128)      v = Wl[(c * 128 + n) * 131 + k];
            else if (n < 256) v = Wr[(c * 128 + (n - 128)) * 131 + k];
            else if (n < 384) v = linsW[(c * 128 + (n - 256)) * 131 + k];
            else              v = (k >= 128) ? We[(c * 128 + (n - 384)) * 3 + (k - 128)]
                                             : 0.0f;
        }
        Wswz[tid] = f2bf(v);
    } else if (tid < P_B1) {                 // bias_cat
        int idx = tid - P_B0;
        int c = idx / JTOT;
        int j = idx - c * JTOT;
        float v;
        if (j < 128)        v = bl[c * 128 + j];
        else if (j < 256)   v = br[c * 128 + (j - 128)];
        else if (j < 384)   v = linsb[c * 128 + (j - 256)];
        else                v = 0.0f;
        bias_cat[idx] = v;
    } else if (tid < P_B2) {                 // Wt0 (read by lin0 in kernel B)
        int idx = tid - P_B1;
        int k = idx / 128;
        int j = idx - k * 128;
        Wt0[idx] = lin0W[j * 64 + k];
    } else if (tid < P_B3) {                 // hswz0 g=4 plane
        int r = tid - P_B2;                  // (mt*64 + l)*8 + j
        int j = r & 7;
        int l = (r >> 3) & 63;
        int mt = r >> 9;
        int row = mt * 16 + (l & 15);
        int k = 128 + (l >> 4) * 8 + j;
        float v = (k < 131) ? pos0[row * 3 + (k - 128)] : 0.0f;
        unsigned short bv = f2bf(v);
        size_t idx = (size_t)((mt * 5 + 4) * 64 + l) * 8 + j;
        hswz0A[idx] = bv;
        hswz0B[idx] = bv;
    } else if (tid < P_B4) {                 // hswz1 g=4 plane (both buffers)
        int r = tid - P_B3;
        int j = r & 7;
        int l = (r >> 3) & 63;
        int mt = r >> 9;
        int row = mt * 16 + (l & 15);
        int k = 128 + (l >> 4) * 8 + j;
        float v = (k < 131) ? pos1[row * 3 + (k - 128)] : 0.0f;
        unsigned short bv = f2bf(v);
        size_t idx = (size_t)((mt * 5 + 4) * 64 + l) * 8 + j;
        hswz1A[idx] = bv;
        hswz1B[idx] = bv;
    }
}

// ---------------------------------------------------------------------------
// Kernel B: knn_merge (blocks 0..127) || lin0 (blocks 128..4223).
// merge reads pb from A (stream-ordered); lin0 reads Wt0 from A (ordered).
// ---------------------------------------------------------------------------
#define MERGE_BLOCKS 128       // 16384 / 128

__global__ __launch_bounds__(128)
void lin0_merge_kernel(const float* __restrict__ latent,
                       const float* __restrict__ Wt0,
                       const float* __restrict__ b,
                       unsigned short* __restrict__ hswz0,
                       const float* __restrict__ pb_d,
                       const int* __restrict__ pb_i,
                       int* __restrict__ knn_idx,
                       float* __restrict__ knn_w) {
    __shared__ float lrow[64];

    if (blockIdx.x < MERGE_BLOCKS) {
        // ---- knn_merge: 16 chunks x 3 entries ----
        int y = blockIdx.x * 128 + threadIdx.x;
        float bd0 = 1e30f, bd1 = 1e30f, bd2 = 1e30f;
        int bi0 = 0, bi1 = 0, bi2 = 0;
        for (int c = 0; c < KCH; ++c) {
            int base = (c * N1 + y) * 3;
#pragma unroll
            for (int t3 = 0; t3 < 3; ++t3) {
                float t = pb_d[base + t3];
                int gi = pb_i[base + t3];
                bool c0 = t < bd0;
                bool c1 = t < bd1;
                bool c2 = t < bd2;
                float n0 = fminf(bd0, t);
                float n1 = __builtin_amdgcn_fmed3f(bd0, bd1, t);
                float n2 = __builtin_amdgcn_fmed3f(bd1, bd2, t);
                int j0 = c0 ? gi : bi0;
                int j1 = c0 ? bi0 : (c1 ? gi : bi1);
                int j2 = c1 ? bi1 : (c2 ? gi : bi2);
                bd0 = n0; bd1 = n1; bd2 = n2;
                bi0 = j0; bi1 = j1; bi2 = j2;
            }
        }
        knn_idx[y * 3]     = bi0;
        knn_idx[y * 3 + 1] = bi1;
        knn_idx[y * 3 + 2] = bi2;
        knn_w[y * 3]     = 1.0f / fmaxf(bd0, 1e-16f);
        knn_w[y * 3 + 1] = 1.0f / fmaxf(bd1, 1e-16f);
        knn_w[y * 3 + 2] = 1.0f / fmaxf(bd2, 1e-16f);
        return;
    }

    // ---- lin0 ----
    int n = blockIdx.x - MERGE_BLOCKS;
    int j = threadIdx.x;
    if (j < 64) lrow[j] = latent[n * 64 + j];
    __syncthreads();
    float acc = b[j];
#pragma unroll 8
    for (int k = 0; k < 64; ++k) acc += lrow[k] * Wt0[k * 128 + j];
    int g = j >> 5, sub = (j >> 3) & 3, jj = j & 7;
    hswz0[(size_t)(((n >> 4) * 5 + g) * 64 + sub * 16 + (n & 15)) * 8 + jj] = f2bf(acc);
}

// ---------------------------------------------------------------------------
// Fused GATv2 layer body.  lin result in LDS (lin_s); gather reduce uses
// 4 DPP stages + 1 swizzle stage.
// mode 0: f32 x out; mode 1: bf16 A-fragments; mode 2: fused output head.
// ---------------------------------------------------------------------------
#define WROW 40
#define FSTR 132

__device__ __forceinline__ void layer_body(
        const unsigned short* __restrict__ hswz,
        const unsigned short* __restrict__ Wswz,
        const float* __restrict__ bias_cat,
        const float* __restrict__ att,
        const float* __restrict__ bias,
        float* __restrict__ xout,
        unsigned short* __restrict__ hout,
        const float* __restrict__ outW,
        const float* __restrict__ outb,
        const float* __restrict__ pos1,
        int mode, int N, int mt0,
        float (*xls_s)[FSTR], float (*pes_s)[FSTR], float (*xr_s)[FSTR],
        float (*lin_s)[FSTR]) {
    int tid = threadIdx.x;
    int w = tid >> 6;               // 0..7
    int l = tid & 63;
    int quad = l >> 4, lcol = l & 15;
    int n0 = mt0 * 16;
    int MT = N >> 4;

    // ---- GEMM phase ----
    bf16x8 a[3][NG];
#pragma unroll
    for (int i = 0; i < 3; ++i) {
        int mt = mt0 - 2 + i;
        if (mt < 0) mt += MT;
#pragma unroll
        for (int g = 0; g < NG; ++g)
            a[i][g] = *(const bf16x8*)&hswz[(size_t)((mt * NG + g) * 64 + l) * 8];
    }

#pragma unroll
    for (int i = 0; i < 4; ++i) {
        int b = i * 8 + w;          // 0..31, wave-uniform
        int colbase = (b & 7) * 16;
        int ntw, kind;              // kind: 0 xl(3mt) 1 pe(3mt) 2 xr 3 lin
        if (b < 8)       { ntw = b;      kind = 0; }
        else if (b < 16) { ntw = 16 + b; kind = 1; }
        else if (b < 24) { ntw = b - 8;  kind = 2; }
        else             { ntw = b - 8;  kind = 3; }
        bf16x8 bf[NG];
#pragma unroll
        for (int g = 0; g < NG; ++g)
            bf[g] = *(const bf16x8*)&Wswz[(size_t)((ntw * NG + g) * 64 + l) * 8];
        float bv = bias_cat[ntw * 16 + lcol];
        if (kind < 2) {
            float (*dst)[FSTR] = (kind == 0) ? xls_s : pes_s;
#pragma unroll
            for (int m = 0; m < 3; ++m) {
                f32x4 c = {bv, bv, bv, bv};
#pragma unroll
                for (int g = 0; g < NG; ++g)
                    c = __builtin_amdgcn_mfma_f32_16x16x32_bf16(a[m][g], bf[g], c, 0, 0, 0);
                if (m == 0) {
                    if (quad >= 2) {
                        int w0 = (quad - 2) * 4;
#pragma unroll
                        for (int r = 0; r < 4; ++r) dst[w0 + r][colbase + lcol] = c[r];
                    }
                } else {
                    int w0 = m * 16 - 8 + quad * 4;
#pragma unroll
                    for (int r = 0; r < 4; ++r) dst[w0 + r][colbase + lcol] = c[r];
                }
            }
        } else {
            f32x4 c = {bv, bv, bv, bv};
#pragma unroll
            for (int g = 0; g < NG; ++g)
                c = __builtin_amdgcn_mfma_f32_16x16x32_bf16(a[2][g], bf[g], c, 0, 0, 0);
            float (*dst)[FSTR] = (kind == 2) ? xr_s : lin_s;
            int w0 = quad * 4;
#pragma unroll
            for (int r = 0; r < 4; ++r) dst[w0 + r][colbase + lcol] = c[r];
        }
    }
    __syncthreads();

    // ---- Gather phase (max-free softmax; 32 lanes x 4 cols per dst row) ----
    int qh = l >> 5;                // 0..1
    int t = l & 31;                 // 0..31
    int dl = w * 2 + qh;            // 0..15
    int d = n0 + dl;
    int selfrow = dl + 24;
    int i0 = t * 4;

    f32x4 linv = *(const f32x4*)&lin_s[dl][i0];

    float att4[4], base[4], xld[4], pesum[4], o[4];
    {
        f32x4 a0 = *(const f32x4*)&att[i0];
        f32x4 r0 = *(const f32x4*)&xr_s[dl][i0];
        f32x4 x0 = *(const f32x4*)&xls_s[selfrow][i0];
        f32x4 p0 = *(const f32x4*)&pes_s[selfrow][i0];
#pragma unroll
        for (int j = 0; j < 4; ++j) {
            att4[j] = a0[j];
            xld[j]  = x0[j];
            base[j] = r0[j] + p0[j];
            pesum[j] = 0.0f;
            o[j] = 0.0f;
        }
    }

    float den = 0.0f;

#pragma unroll
    for (int k = 0; k < NAUG; ++k) {
        int lr = selfrow - c_aug[k];
        float xls[4], pes[4];
        *(f32x4*)&xls[0] = *(const f32x4*)&xls_s[lr][i0];
        *(f32x4*)&pes[0] = *(const f32x4*)&pes_s[lr][i0];
        float p = 0.0f;
#pragma unroll
        for (int j = 0; j < 4; ++j) {
            float mm = xls[j] + base[j] - pes[j];
            mm = mm > 0.0f ? mm : 0.2f * mm;
            p = fmaf(att4[j], mm, p);
            pesum[j] += pes[j];
        }
        p = reduce32(p);
        float wgt = __expf(p);
        den += wgt;
#pragma unroll
        for (int j = 0; j < 4; ++j) o[j] = fmaf(wgt, xls[j], o[j]);
    }
    {   // self loop: eattr = ped - mean(pes); m = xld + base - mean
        const float inv21 = 1.0f / 21.0f;
        float p = 0.0f;
#pragma unroll
        for (int j = 0; j < 4; ++j) {
            float mm = xld[j] + base[j] - pesum[j] * inv21;
            mm = mm > 0.0f ? mm : 0.2f * mm;
            p = fmaf(att4[j], mm, p);
        }
        p = reduce32(p);
        float wgt = __expf(p);
        den += wgt;
#pragma unroll
        for (int j = 0; j < 4; ++j) o[j] = fmaf(wgt, xld[j], o[j]);
    }

    float inv = 1.0f / (den + 1e-16f);
    float res[4];
    {
        f32x4 b0 = *(const f32x4*)&bias[i0];
#pragma unroll
        for (int j = 0; j < 4; ++j) {
            float v = o[j] * inv + b0[j];
            v = v > 0.0f ? v : __expf(v) - 1.0f;
            res[j] = v + linv[j];
        }
    }

    if (mode == 0) {
        *(f32x4*)&xout[(size_t)d * 128 + i0] = *(f32x4*)&res[0];
    } else if (mode == 1) {
        unsigned short ob[4];
#pragma unroll
        for (int j = 0; j < 4; ++j) ob[j] = f2bf(res[j]);
        int g = i0 >> 5, sub = (i0 >> 3) & 3, jj = i0 & 7;
        *(uint2*)&hout[(size_t)((((d >> 4) * 5 + g) * 64) + sub * 16 + (d & 15)) * 8 + jj]
            = *(uint2*)ob;
    } else {                        // mode 2: fused output head
        float po[3];
#pragma unroll
        for (int o3 = 0; o3 < 3; ++o3) {
            const float* wr = &outW[o3 * 131 + i0];
            float p = res[0] * wr[0];
            p = fmaf(res[1], wr[1], p);
            p = fmaf(res[2], wr[2], p);
            p = fmaf(res[3], wr[3], p);
            p = reduce32(p);
            po[o3] = p;
        }
        if (t == 0) {
            float p0 = pos1[d * 3], p1 = pos1[d * 3 + 1], p2 = pos1[d * 3 + 2];
#pragma unroll
            for (int o3 = 0; o3 < 3; ++o3) {
                xout[d * 3 + o3] = po[o3] + outb[o3] + p0 * outW[o3 * 131 + 128]
                                 + p1 * outW[o3 * 131 + 129] + p2 * outW[o3 * 131 + 130];
            }
        }
    }
}

__global__ __launch_bounds__(512, 2)
void fused_layer_kernel(const unsigned short* __restrict__ hswz,
                        const unsigned short* __restrict__ Wswz,
                        const float* __restrict__ bias_cat,
                        const float* __restrict__ att,
                        const float* __restrict__ bias,
                        float* __restrict__ xout,
                        unsigned short* __restrict__ hout,
                        const float* __restrict__ outW,
                        const float* __restrict__ outb,
                        const float* __restrict__ pos1,
                        int mode, int N) {
    __shared__ __align__(16) float xls_s[WROW][FSTR];
    __shared__ __align__(16) float pes_s[WROW][FSTR];
    __shared__ __align__(16) float xr_s[16][FSTR];
    __shared__ __align__(16) float lin_s[16][FSTR];
    layer_body(hswz, Wswz, bias_cat, att, bias, xout, hout,
               outW, outb, pos1, mode, N, blockIdx.x,
               xls_s, pes_s, xr_s, lin_s);
}

// ---------------------------------------------------------------------------
// interp: writes bf16 A-fragments for layer-2 GEMM directly.  One y per
// wave: knn_w/knn_idx read once per wave, bufA gathers are wave-coherent
// coalesced 512B bursts (R11 post-mortem: fusing this into L2 broke both).
// ---------------------------------------------------------------------------
__global__ __launch_bounds__(256)
void interp_kernel(const float* __restrict__ x0, const int* __restrict__ knn_idx,
                   const float* __restrict__ knn_w, unsigned short* __restrict__ hswz) {
    int wave = threadIdx.x >> 6;
    int lane = threadIdx.x & 63;
    int y = blockIdx.x * 4 + wave;
    int i0 = 2 * lane;
    float w0 = knn_w[y * 3], w1 = knn_w[y * 3 + 1], w2 = knn_w[y * 3 + 2];
    int j0 = knn_idx[y * 3], j1 = knn_idx[y * 3 + 1], j2 = knn_idx[y * 3 + 2];
    float inv = 1.0f / (w0 + w1 + w2);
    float2 a = *(const float2*)&x0[(size_t)j0 * 128 + i0];
    float2 b = *(const float2*)&x0[(size_t)j1 * 128 + i0];
    float2 c = *(const float2*)&x0[(size_t)j2 * 128 + i0];
    float rx = (w0 * a.x + w1 * b.x + w2 * c.x) * inv;
    float ry = (w0 * a.y + w1 * b.y + w2 * c.y) * inv;
    unsigned int packed = (unsigned int)f2bf(rx) | ((unsigned int)f2bf(ry) << 16);
    int g = i0 >> 5, sub = (i0 >> 3) & 3, jj = i0 & 7;
    size_t idx = (size_t)((((y >> 4) * 5 + g) * 64) + sub * 16 + (y & 15)) * 8 + jj;
    *(unsigned int*)&hswz[idx] = packed;
}

// ---------------------------------------------------------------------------
extern "C" void kernel_launch(void* const* d_in, const int* in_sizes, int n_in,
                              void* d_out, int out_size, void* d_ws, size_t ws_size,
                              hipStream_t stream) {
    (void)in_sizes; (void)n_in; (void)out_size; (void)ws_size;
    const float* latent   = (const float*)d_in[0];
    const float* pos0     = (const float*)d_in[1];
    const float* pos1     = (const float*)d_in[2];
    const float* conv_Wl  = (const float*)d_in[5];
    const float* conv_bl  = (const float*)d_in[6];
    const float* conv_Wr  = (const float*)d_in[7];
    const float* conv_br  = (const float*)d_in[8];
    const float* conv_We  = (const float*)d_in[9];
    const float* conv_att = (const float*)d_in[10];
    const float* conv_bias= (const float*)d_in[11];
    const float* lin0_W   = (const float*)d_in[12];
    const float* lin0_b   = (const float*)d_in[13];
    const float* lins_W   = (const float*)d_in[14];
    const float* lins_b   = (const float*)d_in[15];
    const float* out_W    = (const float*)d_in[16];
    const float* out_b    = (const float*)d_in[17];
    float* out = (float*)d_out;

    char* ws = (char*)d_ws;
    unsigned short* Wswz = (unsigned short*)ws; ws += (size_t)4 * WSWZ_PER_LAYER * 2;
    float* bias_cat = (float*)ws;  ws += (size_t)4 * JTOT * 4;
    float* Wt0      = (float*)ws;  ws += (size_t)64 * 128 * 4;
    unsigned short* hswz0A = (unsigned short*)ws; ws += (size_t)(N0 / 16) * NG * 64 * 8 * 2;
    unsigned short* hswz0B = (unsigned short*)ws; ws += (size_t)(N0 / 16) * NG * 64 * 8 * 2;
    unsigned short* hswz1A = (unsigned short*)ws; ws += (size_t)(N1 / 16) * NG * 64 * 8 * 2;
    unsigned short* hswz1B = (unsigned short*)ws; ws += (size_t)(N1 / 16) * NG * 64 * 8 * 2;
    float* bufA     = (float*)ws;  ws += (size_t)N0 * 128 * 4;
    float* pb_d     = (float*)ws;  ws += (size_t)KCH * N1 * 3 * 4;
    int*   pb_i     = (int*)ws;    ws += (size_t)KCH * N1 * 3 * 4;
    int*   knn_idx  = (int*)ws;    ws += (size_t)N1 * 3 * 4;
    float* knn_w    = (float*)ws;  ws += (size_t)N1 * 3 * 4;

    // A: knn_part (1024 blocks, first) || prep (3880 blocks)
    prep_knn_kernel<<<KNN_BLOCKS + PREP_BLOCKS, 256, 0, stream>>>(
        conv_Wl, conv_Wr, conv_We, lins_W, conv_bl, conv_br, lins_b, lin0_W,
        pos0, pos1, Wswz, bias_cat, Wt0, hswz0A, hswz0B, hswz1A, hswz1B,
        pb_d, pb_i);

    // B: knn_merge (128 blocks) || lin0 (4096 blocks)
    lin0_merge_kernel<<<MERGE_BLOCKS + N0, 128, 0, stream>>>(
        latent, Wt0, lin0_b, hswz0A, pb_d, pb_i, knn_idx, knn_w);

    // layer 0: h0A -> h0B (bf16 frags);  layer 1: h0B -> bufA (f32)
    fused_layer_kernel<<<N0 / 16, 512, 0, stream>>>(
        hswz0A, Wswz + (size_t)0 * WSWZ_PER_LAYER, bias_cat + 0 * JTOT,
        conv_att + 0 * 128, conv_bias + 0 * 128, nullptr, hswz0B,
        nullptr, nullptr, nullptr, 1, N0);
    fused_layer_kernel<<<N0 / 16, 512, 0, stream>>>(
        hswz0B, Wswz + (size_t)1 * WSWZ_PER_LAYER, bias_cat + 1 * JTOT,
        conv_att + 1 * 128, conv_bias + 1 * 128, bufA, nullptr,
        nullptr, nullptr, nullptr, 0, N0);

    interp_kernel<<<N1 / 4, 256, 0, stream>>>(bufA, knn_idx, knn_w, hswz1A);

    // layer 2: h1A -> h1B;  layer 3: h1B -> out (fused output head)
    fused_layer_kernel<<<N1 / 16, 512, 0, stream>>>(
        hswz1A, Wswz + (size_t)2 * WSWZ_PER_LAYER, bias_cat + 2 * JTOT,
        conv_att + 2 * 128, conv_bias + 2 * 128, nullptr, hswz1B,
        nullptr, nullptr, nullptr, 1, N1);
    fused_layer_kernel<<<N1 / 16, 512, 0, stream>>>(
        hswz1B, Wswz + (size_t)3 * WSWZ_PER_LAYER, bias_cat + 3 * JTOT,
        conv_att + 3 * 128, conv_bias + 3 * 128, out, nullptr,
        out_W, out_b, pos1, 2, N1);
}